// Round 1
// baseline (697.853 us; speedup 1.0000x reference)
//
#include <hip/hip_runtime.h>
#include <hip/hip_bf16.h>

#define NTAGS 128
#define TLEN 512
#define BATCH 512
#define START_ID 0
#define END_ID 1

// ---------------------------------------------------------------------------
// Gold score: per batch, gather emissions/transitions along the tag path.
// ---------------------------------------------------------------------------
__global__ __launch_bounds__(256) void k_gold(
    const float* __restrict__ x, const int* __restrict__ tags,
    const float* __restrict__ mask, const float* __restrict__ transition,
    float* __restrict__ gold)
{
  const int b = blockIdx.x;
  const int tid = threadIdx.x;
  const int* tb = tags + b * (TLEN + 1);
  const float* mb = mask + b * TLEN;
  const float* xb = x + (size_t)b * TLEN * NTAGS;

  float s = 0.f, lensum = 0.f;
  for (int t = tid; t < TLEN; t += 256) {
    int to = tb[t + 1];
    int from = tb[t];
    float m = mb[t];
    float emit = xb[(size_t)t * NTAGS + to];
    float tr = transition[to * NTAGS + from];
    s += (emit + tr) * m;
    lensum += m;
  }
  // wave reduce (64 lanes)
  for (int off = 32; off > 0; off >>= 1) {
    s += __shfl_xor(s, off);
    lensum += __shfl_xor(lensum, off);
  }
  __shared__ float rs[4], rl[4];
  int wid = tid >> 6;
  if ((tid & 63) == 0) { rs[wid] = s; rl[wid] = lensum; }
  __syncthreads();
  if (tid == 0) {
    float st = rs[0] + rs[1] + rs[2] + rs[3];
    float lt = rl[0] + rl[1] + rl[2] + rl[3];
    int len = (int)lt;                       // lengths = sum(mask) as int
    int last = tb[len];
    gold[b] = st + transition[END_ID * NTAGS + last];
  }
}

// ---------------------------------------------------------------------------
// Forward algorithm. One block per batch; thread i owns alpha_i.
// logsumexp_j(alpha_j + T_ij) = C + log( sum_j exp(alpha_j - C) * E_ij ),
// E = exp(T) held in registers (row i per thread), C = alpha[0] (so the
// dot is never zero: p_0 == 1). Alpha spread is bounded (~±14) so exp is
// always in fp32 range without a max-reduce.
// ---------------------------------------------------------------------------
__global__ __launch_bounds__(128, 2) void k_forward(
    const float* __restrict__ x, const float* __restrict__ mask,
    const float* __restrict__ transition, const float* __restrict__ gold,
    float* __restrict__ out)
{
  const int b = blockIdx.x;
  const int i = threadIdx.x;  // tag row 0..127

  __shared__ __align__(16) float p_lds[NTAGS];
  __shared__ float c_lds;
  __shared__ float red2[2];

  // E row i = exp(transition[i][:]) into 32 float4 registers.
  float4 e[32];
  const float4* trow = reinterpret_cast<const float4*>(transition + i * NTAGS);
  #pragma unroll
  for (int k = 0; k < 32; ++k) {
    float4 tv = trow[k];
    e[k].x = __expf(tv.x); e[k].y = __expf(tv.y);
    e[k].z = __expf(tv.z); e[k].w = __expf(tv.w);
  }
  const float tend = transition[END_ID * NTAGS + i];

  float alpha = (i == START_ID) ? 0.0f : -10000.0f;
  if (i == 0) c_lds = 0.0f;
  __syncthreads();

  const float* xb = x + (size_t)b * TLEN * NTAGS;
  const float* mb = mask + b * TLEN;

  float emit_cur = xb[i];
  float m_cur = mb[0];

  for (int t = 0; t < TLEN; ++t) {
    // prefetch next step's emission/mask (hides HBM latency under the dot)
    float emit_nxt = 0.f, m_nxt = 0.f;
    if (t + 1 < TLEN) {
      emit_nxt = xb[(size_t)(t + 1) * NTAGS + i];
      m_nxt = mb[t + 1];
    }

    float C = c_lds;                  // alpha[0] from previous step
    float p = __expf(alpha - C);
    p_lds[i] = p;
    __syncthreads();                  // barrier 1: p published

    // dot_i = sum_j p[j] * E[i][j]; p reads are wave-uniform broadcasts.
    float a0 = 0.f, a1 = 0.f, a2 = 0.f, a3 = 0.f;
    const float4* p4 = reinterpret_cast<const float4*>(p_lds);
    #pragma unroll
    for (int k = 0; k < 32; ++k) {
      float4 pv = p4[k];
      a0 = fmaf(pv.x, e[k].x, a0);
      a1 = fmaf(pv.y, e[k].y, a1);
      a2 = fmaf(pv.z, e[k].z, a2);
      a3 = fmaf(pv.w, e[k].w, a3);
    }
    float dot = (a0 + a1) + (a2 + a3);

    float na = emit_cur + C + __logf(dot);
    alpha = (m_cur > 0.0f) ? na : alpha;
    if (i == 0) c_lds = alpha;        // publish next C (after barrier 1, so
                                      // no race with this step's C reads)
    __syncthreads();                  // barrier 2: p_lds reads done + C visible

    emit_cur = emit_nxt;
    m_cur = m_nxt;
  }

  // final: logsumexp_i(alpha_i + T[END][i])
  float Cf = c_lds;
  float v = __expf(alpha + tend - Cf);
  for (int off = 32; off > 0; off >>= 1) v += __shfl_xor(v, off);
  if ((i & 63) == 0) red2[i >> 6] = v;
  __syncthreads();
  if (i == 0) {
    float fwd = Cf + __logf(red2[0] + red2[1]);
    out[b] = fwd - gold[b];
  }
}

extern "C" void kernel_launch(void* const* d_in, const int* in_sizes, int n_in,
                              void* d_out, int out_size, void* d_ws, size_t ws_size,
                              hipStream_t stream) {
  const float* x          = (const float*)d_in[0];
  const int*   tags       = (const int*)d_in[1];
  const float* mask       = (const float*)d_in[2];
  const float* transition = (const float*)d_in[3];
  float* out  = (float*)d_out;
  float* gold = (float*)d_ws;   // 512 floats of scratch

  k_gold<<<BATCH, 256, 0, stream>>>(x, tags, mask, transition, gold);
  k_forward<<<BATCH, 128, 0, stream>>>(x, mask, transition, gold, out);
}

// Round 5
// 628.284 us; speedup vs baseline: 1.1107x; 1.1107x over previous
//
#include <hip/hip_runtime.h>
#include <hip/hip_bf16.h>

#define NTAGS 128
#define TLEN 512
#define BATCH 512
#define START_ID 0
#define END_ID 1

#define REP32(M) M(0) M(1) M(2) M(3) M(4) M(5) M(6) M(7) \
                 M(8) M(9) M(10) M(11) M(12) M(13) M(14) M(15) \
                 M(16) M(17) M(18) M(19) M(20) M(21) M(22) M(23) \
                 M(24) M(25) M(26) M(27) M(28) M(29) M(30) M(31)

// One block per batch; thread i owns tag-row i. Normal-space recurrence:
//   p_i(t+1) = dot_i(t) * exp(emit_t[i]) / S_t,  dot_i = sum_j E[i][j] p_j,
//   E = exp(T) held in 32 NAMED float4 registers (no array -> no scratch).
// S_t = sum of p_lds[j], j%4==0 — computed identically by all threads from
// the same LDS values (uniform, no broadcast needed). C accumulates as
// Clog += log(S_t) off the critical path. One barrier/step (p double-buffer).
__global__ __launch_bounds__(128, 2) void k_crf(
    const float* __restrict__ x, const int* __restrict__ tags,
    const float* __restrict__ mask, const float* __restrict__ transition,
    float* __restrict__ out)
{
  const int b = blockIdx.x;
  const int i = threadIdx.x;  // 0..127

  __shared__ __align__(16) float p_lds[2][NTAGS];
  __shared__ float red_lds[4];

  const float* xb = x + (size_t)b * TLEN * NTAGS;
  const float* mb = mask + b * TLEN;
  const int*   tb = tags + b * (TLEN + 1);

  // ---------------- gold score (fused prologue) ----------------
  float gs = 0.f, msum = 0.f;
  #pragma unroll
  for (int r = 0; r < 4; ++r) {
    int t = i + r * 128;
    int to = tb[t + 1];
    int from = tb[t];
    float m = mb[t];
    gs += (xb[(size_t)t * NTAGS + to] + transition[to * NTAGS + from]) * m;
    msum += m;
  }
  #pragma unroll
  for (int off = 32; off > 0; off >>= 1) {
    gs += __shfl_xor(gs, off);
    msum += __shfl_xor(msum, off);
  }
  if ((i & 63) == 0) { red_lds[i >> 6] = gs; red_lds[2 + (i >> 6)] = msum; }
  __syncthreads();
  float gold_s = 0.f;
  if (i == 0) {
    float gt = red_lds[0] + red_lds[1];
    int len = (int)(red_lds[2] + red_lds[3]);   // exact: sum of 0/1 floats
    gold_s = gt + transition[END_ID * NTAGS + tb[len]];
  }

  // ---------------- E row i -> 32 named float4 registers ----------------
  const float4* trow = reinterpret_cast<const float4*>(transition + i * NTAGS);
#define E_DECL(n) float4 e##n;
  REP32(E_DECL)
#define E_INIT(n) { float4 tv = trow[n]; \
    e##n.x = __expf(tv.x); e##n.y = __expf(tv.y); \
    e##n.z = __expf(tv.z); e##n.w = __expf(tv.w); }
  REP32(E_INIT)
  const float etend = __expf(transition[END_ID * NTAGS + i]);

  // ---------------- forward scan ----------------
  float p = (i == START_ID) ? 1.0f : 0.0f;   // exp(alpha - C), C=0
  float Clog = 0.0f;
  float s_cur = __expf(xb[i]);               // exp(emit_0[i])
  float m_cur = mb[0];

  int buf = 0;
  for (int t = 0; t < TLEN; ++t) {
    p_lds[buf][i] = p;
    __syncthreads();                         // the only barrier per step

    // prefetch next step's emission/mask (clamped; hides under the dot)
    int tn = (t + 1 < TLEN) ? (t + 1) : (TLEN - 1);
    float emit_nxt = xb[(size_t)tn * NTAGS + i];
    float m_nxt = mb[tn];

    const float4* p4 = reinterpret_cast<const float4*>(p_lds[buf]);
    float a0 = 0.f, a1 = 0.f, a2 = 0.f, a3 = 0.f, S = 0.f;
#define E_FMA(n) { float4 pv = p4[n]; \
    a0 = fmaf(pv.x, e##n.x, a0); a1 = fmaf(pv.y, e##n.y, a1); \
    a2 = fmaf(pv.z, e##n.z, a2); a3 = fmaf(pv.w, e##n.w, a3); \
    S += pv.x; }
    REP32(E_FMA)
    float dot = (a0 + a1) + (a2 + a3);

    // S: uniform subset-normalizer (includes j=0, so S=1 at t=0; p>0 for all
    // j after step 1 -> S>0 always; magnitudes provably stay in fp32 range).
    float r = 1.0f / S;
    float pn = dot * s_cur * r;
    bool upd = (m_cur > 0.0f);
    p = upd ? pn : p;
    Clog += upd ? __logf(S) : 0.0f;          // off critical path

    s_cur = __expf(emit_nxt);                // off critical path
    m_cur = m_nxt;
    buf ^= 1;
  }

  // ---------------- final logsumexp + output ----------------
  float v = p * etend;                       // p_i * exp(T[END][i])
  #pragma unroll
  for (int off = 32; off > 0; off >>= 1) v += __shfl_xor(v, off);
  if ((i & 63) == 0) red_lds[i >> 6] = v;    // ordered vs prologue reads by
  __syncthreads();                           // the 512 main-loop barriers
  if (i == 0) {
    out[b] = Clog + __logf(red_lds[0] + red_lds[1]) - gold_s;
  }
}

extern "C" void kernel_launch(void* const* d_in, const int* in_sizes, int n_in,
                              void* d_out, int out_size, void* d_ws, size_t ws_size,
                              hipStream_t stream) {
  const float* x          = (const float*)d_in[0];
  const int*   tags       = (const int*)d_in[1];
  const float* mask       = (const float*)d_in[2];
  const float* transition = (const float*)d_in[3];
  float* out = (float*)d_out;

  k_crf<<<BATCH, NTAGS, 0, stream>>>(x, tags, mask, transition, out);
}

// Round 6
// 499.426 us; speedup vs baseline: 1.3973x; 1.2580x over previous
//
#include <hip/hip_runtime.h>
#include <hip/hip_bf16.h>

#define NTAGS 128
#define TLEN 512
#define BATCH 512
#define START_ID 0
#define END_ID 1

#define REP16(M) M(0) M(1) M(2) M(3) M(4) M(5) M(6) M(7) \
                 M(8) M(9) M(10) M(11) M(12) M(13) M(14) M(15)

// 256 threads/block, one block per batch. Thread j owns HALF a tag-row:
// row r=j>>1, half h=j&1 -> E half-row = 16 named float4 (64 VGPR), which
// the allocator keeps resident (R5 showed 32 float4 gets demoted: VGPR=108).
// Normal-space recurrence, half-dots combined via shfl_xor(.,1) (partner is
// the adjacent lane). S = uniform subset-normalizer sum(p[4k]); Clog += log S
// off the critical path. One barrier/step via double-buffered p_lds.
__global__ __launch_bounds__(256, 2) void k_crf(
    const float* __restrict__ x, const int* __restrict__ tags,
    const float* __restrict__ mask, const float* __restrict__ transition,
    float* __restrict__ out)
{
  const int b = blockIdx.x;
  const int j = threadIdx.x;   // 0..255
  const int r = j >> 1;        // tag row 0..127
  const int h = j & 1;         // which half of the row

  __shared__ __align__(16) float p_lds[2][NTAGS];
  __shared__ float red_lds[8];

  const float* xb = x + (size_t)b * TLEN * NTAGS;
  const float* mb = mask + b * TLEN;
  const int*   tb = tags + b * (TLEN + 1);

  // ---------------- gold score (fused prologue) ----------------
  float gs = 0.f, msum = 0.f;
  #pragma unroll
  for (int rr = 0; rr < 2; ++rr) {
    int t = j + rr * 256;
    int to = tb[t + 1];
    int from = tb[t];
    float m = mb[t];
    gs += (xb[(size_t)t * NTAGS + to] + transition[to * NTAGS + from]) * m;
    msum += m;
  }
  #pragma unroll
  for (int off = 32; off > 0; off >>= 1) {
    gs += __shfl_xor(gs, off);
    msum += __shfl_xor(msum, off);
  }
  int wid = j >> 6;
  if ((j & 63) == 0) { red_lds[wid] = gs; red_lds[4 + wid] = msum; }
  __syncthreads();
  float gold_s = 0.f;
  if (j == 0) {
    float gt = red_lds[0] + red_lds[1] + red_lds[2] + red_lds[3];
    int len = (int)(red_lds[4] + red_lds[5] + red_lds[6] + red_lds[7]);
    gold_s = gt + transition[END_ID * NTAGS + tb[len]];
  }

  // -------- E half-row -> 16 named float4 registers (64 VGPR) --------
  const float4* trow =
      reinterpret_cast<const float4*>(transition + r * NTAGS + h * 64);
#define E_DECL(n) float4 e##n;
  REP16(E_DECL)
#define E_INIT(n) { float4 tv = trow[n]; \
    e##n.x = __expf(tv.x); e##n.y = __expf(tv.y); \
    e##n.z = __expf(tv.z); e##n.w = __expf(tv.w); }
  REP16(E_INIT)
  const float etend = __expf(transition[END_ID * NTAGS + r]);

  // ---------------- forward scan ----------------
  float p = (r == START_ID) ? 1.0f : 0.0f;   // both halves hold row state
  float Clog = 0.0f;
  float s_cur = __expf(xb[r]);               // exp(emit_0[r])
  float m_cur = mb[0];

  int buf = 0;
  for (int t = 0; t < TLEN; ++t) {
    if (h == 0) p_lds[buf][r] = p;           // even lanes: rows, conflict-free
    __syncthreads();                         // the only barrier per step

    // prefetch next step's emission/mask (hides under the dot)
    int tn = (t + 1 < TLEN) ? (t + 1) : (TLEN - 1);
    float emit_nxt = xb[(size_t)tn * NTAGS + r];
    float m_nxt = mb[tn];

    // half-dot over 64 entries; p reads are 2-address wave broadcasts (free)
    const float4* p4 =
        reinterpret_cast<const float4*>(p_lds[buf]) + h * 16;
    float a0 = 0.f, a1 = 0.f, a2 = 0.f, a3 = 0.f, S = 0.f;
#define E_FMA(n) { float4 pv = p4[n]; \
    a0 = fmaf(pv.x, e##n.x, a0); a1 = fmaf(pv.y, e##n.y, a1); \
    a2 = fmaf(pv.z, e##n.z, a2); a3 = fmaf(pv.w, e##n.w, a3); \
    S += pv.x; }
    REP16(E_FMA)
    float dot = (a0 + a1) + (a2 + a3);
    dot += __shfl_xor(dot, 1);               // combine the two halves
    S   += __shfl_xor(S, 1);                 // full subset-normalizer

    float pn = dot * s_cur * (1.0f / S);
    bool upd = (m_cur > 0.0f);
    p = upd ? pn : p;
    Clog += upd ? __logf(S) : 0.0f;          // off critical path

    s_cur = __expf(emit_nxt);                // off critical path
    m_cur = m_nxt;
    buf ^= 1;
  }

  // ---------------- final logsumexp + output ----------------
  float v = (h == 0) ? p * etend : 0.0f;     // count each row once
  #pragma unroll
  for (int off = 32; off > 0; off >>= 1) v += __shfl_xor(v, off);
  if ((j & 63) == 0) red_lds[wid] = v;       // ordered vs prologue by the
  __syncthreads();                           // 512 main-loop barriers
  if (j == 0) {
    float tot = red_lds[0] + red_lds[1] + red_lds[2] + red_lds[3];
    out[b] = Clog + __logf(tot) - gold_s;
  }
}

extern "C" void kernel_launch(void* const* d_in, const int* in_sizes, int n_in,
                              void* d_out, int out_size, void* d_ws, size_t ws_size,
                              hipStream_t stream) {
  const float* x          = (const float*)d_in[0];
  const int*   tags       = (const int*)d_in[1];
  const float* mask       = (const float*)d_in[2];
  const float* transition = (const float*)d_in[3];
  float* out = (float*)d_out;

  k_crf<<<BATCH, 256, 0, stream>>>(x, tags, mask, transition, out);
}